// Round 6
// baseline (6098.134 us; speedup 1.0000x reference)
//
#include <hip/hip_runtime.h>
#include <hip/hip_bf16.h>
#include <type_traits>

typedef _Float16 half8_t __attribute__((ext_vector_type(8)));
typedef _Float16 half4_t __attribute__((ext_vector_type(4)));
typedef float f32x4 __attribute__((ext_vector_type(4)));

// ---------------- CSR build ----------------
// harness delivers integer inputs as int32 (edge_index int64 -> const int*).

static __global__ __launch_bounds__(256) void k_zero(int* __restrict__ a, int n) {
  int i = blockIdx.x * 256 + threadIdx.x;
  if (i < n) a[i] = 0;
}

static __global__ __launch_bounds__(256) void k_deg(const int* __restrict__ ei,
                                                    int* __restrict__ deg, int E) {
  int e = blockIdx.x * 256 + threadIdx.x;
  if (e < E) atomicAdd(&deg[ei[E + e]], 1);  // dst = ei[1][e]
}

static __global__ __launch_bounds__(256) void k_chunk_sum(const int* __restrict__ deg,
                                                          int* __restrict__ bsum, int n) {
  int t = threadIdx.x;
  int base = blockIdx.x * 1024 + t * 4;
  int s = 0;
#pragma unroll
  for (int j = 0; j < 4; j++) {
    int idx = base + j;
    if (idx < n) s += deg[idx];
  }
  __shared__ int red[256];
  red[t] = s;
  __syncthreads();
  for (int off = 128; off > 0; off >>= 1) {
    if (t < off) red[t] += red[t + off];
    __syncthreads();
  }
  if (t == 0) bsum[blockIdx.x] = red[0];
}

static __global__ void k_scan_bsum(int* bsum, int nb) {
  if (threadIdx.x == 0 && blockIdx.x == 0) {
    int run = 0;
    for (int i = 0; i < nb; i++) {
      int v = bsum[i];
      bsum[i] = run;
      run += v;
    }
  }
}

static __global__ __launch_bounds__(256) void k_scan_final(const int* __restrict__ deg,
                                                           const int* __restrict__ bsum,
                                                           int* __restrict__ rs,
                                                           float* __restrict__ dinv,
                                                           int n, int Etot) {
  int t = threadIdx.x;
  int base = blockIdx.x * 1024 + t * 4;
  int v[4];
  int s = 0;
#pragma unroll
  for (int j = 0; j < 4; j++) {
    int idx = base + j;
    v[j] = (idx < n) ? deg[idx] : 0;
    s += v[j];
  }
  __shared__ int sc[256];
  sc[t] = s;
  __syncthreads();
  for (int off = 1; off < 256; off <<= 1) {
    int add = (t >= off) ? sc[t - off] : 0;
    __syncthreads();
    sc[t] += add;
    __syncthreads();
  }
  int run = sc[t] - s + bsum[blockIdx.x];
#pragma unroll
  for (int j = 0; j < 4; j++) {
    int idx = base + j;
    if (idx < n) {
      rs[idx] = run;
      dinv[idx] = v[j] > 0 ? 1.0f / (float)v[j] : 0.0f;
      run += v[j];
    }
  }
  if (blockIdx.x == 0 && t == 0) rs[n] = Etot;
}

static __global__ __launch_bounds__(256) void k_fill(const int* __restrict__ ei,
                                                     const int* __restrict__ rs,
                                                     int* __restrict__ cursor,
                                                     int* __restrict__ srcs,
                                                     int* __restrict__ dsts, int E) {
  int e = blockIdx.x * 256 + threadIdx.x;
  if (e < E) {
    int d = ei[E + e];
    int s = ei[e];
    int pos = atomicAdd(&cursor[d], 1);
    srcs[rs[d] + pos] = s;
    dsts[rs[d] + pos] = d;
  }
}

// ---------------- casts ----------------

static __global__ __launch_bounds__(256) void k_cast_f16(const float* __restrict__ in,
                                                         _Float16* __restrict__ out, int n4) {
  int i = blockIdx.x * 256 + threadIdx.x;
  if (i < n4) {
    float4 v = reinterpret_cast<const float4*>(in)[i];
    half4_t h;
    h[0] = (_Float16)v.x;
    h[1] = (_Float16)v.y;
    h[2] = (_Float16)v.z;
    h[3] = (_Float16)v.w;
    reinterpret_cast<half4_t*>(out)[i] = h;
  }
}

// ---------------- fused layer: edge-parallel mean-agg (LDS f32 atomics) + dual GEMM ----------------
// Block: 256 threads = 4 waves, owns 64 dst rows = one contiguous CSR edge range.
// Phase 1: waves consume edges interleaved (stride 4, unroll 4). Per edge, the wave's
//   64 lanes load cols l+64j of the src row (128B coalesced) and ds_add_f32 into a
//   64xDIN f32 LDS tile. XOR swizzle (c ^ ((r&7)<<2)) keeps atomics AND the phase-2
//   f32x4 fragment reads at 2-way bank aliasing (free).
// Phase 2: out[i][o] = relu(b[o] + mean[i]·Wl[o] + x[i]·Wr[o]); A first half from LDS
//   (acc*dinv -> f16), second half from global x; B = L2-resident weights.

template <int DIN, bool LAST>
static __global__ __launch_bounds__(256) void k_fused(const _Float16* __restrict__ x,
                                                      const int* __restrict__ srcs,
                                                      const int* __restrict__ dsts,
                                                      const int* __restrict__ rs,
                                                      const float* __restrict__ dinv,
                                                      const _Float16* __restrict__ wl,
                                                      const _Float16* __restrict__ wr,
                                                      const float* __restrict__ bias,
                                                      _Float16* __restrict__ yout,
                                                      float* __restrict__ fout, int n) {
  constexpr int EPL = DIN / 64;  // elements per lane per row (strided by 64)
  __shared__ __align__(16) float accT[64 * DIN];
  int lane = threadIdx.x & 63;
  int w = threadIdx.x >> 6;
  int i0 = blockIdx.x * 64;

  // zero accumulators
  {
    f32x4* p4 = (f32x4*)accT;
    constexpr int tot = 64 * DIN / 4;
#pragma unroll
    for (int i = 0; i < tot / 256; ++i) p4[i * 256 + threadIdx.x] = (f32x4)0.0f;
  }
  __syncthreads();

  // ---- phase 1: edge-parallel accumulate ----
  int rhi = i0 + 64;
  if (rhi > n) rhi = n;
  int elo = rs[i0], ehi = rs[rhi];
  int e = elo + w;
  for (; e + 12 < ehi; e += 16) {  // 4 edges per wave-iteration
    int s0 = srcs[e], s1 = srcs[e + 4], s2 = srcs[e + 8], s3 = srcs[e + 12];
    int d0 = dsts[e], d1 = dsts[e + 4], d2 = dsts[e + 8], d3 = dsts[e + 12];
    _Float16 h0[EPL], h1[EPL], h2[EPL], h3[EPL];
#pragma unroll
    for (int j = 0; j < EPL; j++) {
      int c = lane + 64 * j;
      h0[j] = x[(size_t)s0 * DIN + c];
      h1[j] = x[(size_t)s1 * DIN + c];
      h2[j] = x[(size_t)s2 * DIN + c];
      h3[j] = x[(size_t)s3 * DIN + c];
    }
    int r0 = d0 - i0, r1 = d1 - i0, r2 = d2 - i0, r3 = d3 - i0;
#pragma unroll
    for (int j = 0; j < EPL; j++) {
      int c = lane + 64 * j;
      atomicAdd(&accT[r0 * DIN + (c ^ ((r0 & 7) << 2))], (float)h0[j]);
      atomicAdd(&accT[r1 * DIN + (c ^ ((r1 & 7) << 2))], (float)h1[j]);
      atomicAdd(&accT[r2 * DIN + (c ^ ((r2 & 7) << 2))], (float)h2[j]);
      atomicAdd(&accT[r3 * DIN + (c ^ ((r3 & 7) << 2))], (float)h3[j]);
    }
  }
  for (; e < ehi; e += 4) {  // tail
    int s = srcs[e];
    int r = dsts[e] - i0;
#pragma unroll
    for (int j = 0; j < EPL; j++) {
      int c = lane + 64 * j;
      atomicAdd(&accT[r * DIN + (c ^ ((r & 7) << 2))], (float)x[(size_t)s * DIN + c]);
    }
  }
  __syncthreads();

  // ---- phase 2: dual GEMM ----
  int lr = lane & 15;
  int kq = lane >> 4;
  int n0 = w * 64;
  float dim[4];
#pragma unroll
  for (int m = 0; m < 4; m++) {
    int row = i0 + m * 16 + lr;
    dim[m] = dinv[row < n ? row : n - 1];
  }
  f32x4 acc2[4][4];
#pragma unroll
  for (int m = 0; m < 4; m++)
#pragma unroll
    for (int nn = 0; nn < 4; nn++) acc2[m][nn] = (f32x4)0.0f;

#pragma unroll 2
  for (int ks = 0; ks < DIN / 16; ++ks) {  // 2*DIN / 32 k-steps
    int k0 = ks * 32;
    half8_t a[4], b[4];
    if (k0 < DIN) {
#pragma unroll
      for (int m = 0; m < 4; m++) {
        int r = m * 16 + lr;
        int swz = (r & 7) << 2;
        int c0 = k0 + kq * 8;
        f32x4 lo = *(const f32x4*)&accT[r * DIN + (c0 ^ swz)];
        f32x4 hi = *(const f32x4*)&accT[r * DIN + ((c0 + 4) ^ swz)];
        half8_t av;
#pragma unroll
        for (int i2 = 0; i2 < 4; i2++) {
          av[i2] = (_Float16)(lo[i2] * dim[m]);
          av[i2 + 4] = (_Float16)(hi[i2] * dim[m]);
        }
        a[m] = av;
      }
#pragma unroll
      for (int nn = 0; nn < 4; nn++) {
        int col = n0 + nn * 16 + lr;
        b[nn] = *(const half8_t*)(wl + (size_t)col * DIN + k0 + kq * 8);
      }
    } else {
      int kk = k0 - DIN;
#pragma unroll
      for (int m = 0; m < 4; m++) {
        int row = i0 + m * 16 + lr;
        if (row >= n) row = n - 1;  // clamp; stores guarded
        a[m] = *(const half8_t*)(x + (size_t)row * DIN + kk + kq * 8);
      }
#pragma unroll
      for (int nn = 0; nn < 4; nn++) {
        int col = n0 + nn * 16 + lr;
        b[nn] = *(const half8_t*)(wr + (size_t)col * DIN + kk + kq * 8);
      }
    }
#pragma unroll
    for (int m = 0; m < 4; m++)
#pragma unroll
      for (int nn = 0; nn < 4; nn++)
        acc2[m][nn] = __builtin_amdgcn_mfma_f32_16x16x32_f16(a[m], b[nn], acc2[m][nn], 0, 0, 0);
  }

  // ---- epilogue ----
#pragma unroll
  for (int nn = 0; nn < 4; nn++) {
    int col = n0 + nn * 16 + lr;  // D col = lane&15
    float bv = bias[col];
#pragma unroll
    for (int m = 0; m < 4; m++) {
#pragma unroll
      for (int r = 0; r < 4; r++) {
        int row = i0 + m * 16 + kq * 4 + r;  // D row = (lane>>4)*4 + r
        if (row < n) {
          float v = acc2[m][nn][r] + bv;
          v = v > 0.0f ? v : 0.0f;
          if constexpr (LAST)
            fout[(size_t)row * 256 + col] = v;
          else
            yout[(size_t)row * 256 + col] = (_Float16)v;
        }
      }
    }
  }
}

// ---------------- host launch ----------------
// ws  : xbuf(51.2M) srcs(6.4M) dsts(6.4M) rs deg cursor dinv bsum weights(f16) ~= 68 MB
// dout: [0,51.2M) y0 f16 (L0 out); [51.2M,76.8M) x0 f16 (feature cast);
//       final fused layer reads only ws (xbuf) and writes full d_out f32 last.

extern "C" void kernel_launch(void* const* d_in, const int* in_sizes, int n_in,
                              void* d_out, int out_size, void* d_ws, size_t ws_size,
                              hipStream_t stream) {
  const float* feat = (const float*)d_in[0];
  const int* ei = (const int*)d_in[1];
  const float* Wl[3] = {(const float*)d_in[2], (const float*)d_in[5], (const float*)d_in[8]};
  const float* Wr[3] = {(const float*)d_in[3], (const float*)d_in[6], (const float*)d_in[9]};
  const float* Bv[3] = {(const float*)d_in[4], (const float*)d_in[7], (const float*)d_in[10]};
  int N = in_sizes[0] / 128;
  int E = in_sizes[1] / 2;

  char* p = (char*)d_ws;
  auto carve = [&](size_t bytes) {
    char* r = p;
    p += (bytes + 255) & ~(size_t)255;
    return r;
  };
  _Float16* xbuf = (_Float16*)carve((size_t)N * 256 * 2);  // layer-1 output
  int* srcs = (int*)carve((size_t)E * 4);
  int* dsts = (int*)carve((size_t)E * 4);
  int* rs = (int*)carve((size_t)(N + 1) * 4);
  int* deg = (int*)carve((size_t)N * 4);
  int* cursor = (int*)carve((size_t)N * 4);
  float* dinv = (float*)carve((size_t)N * 4);
  int* bsum = (int*)carve(4096);
  const int din[3] = {128, 256, 256};
  _Float16* wlh[3];
  _Float16* wrh[3];
  for (int l = 0; l < 3; l++) {
    wlh[l] = (_Float16*)carve((size_t)256 * din[l] * 2);
    wrh[l] = (_Float16*)carve((size_t)256 * din[l] * 2);
  }

  _Float16* y0 = (_Float16*)d_out;                             // [N][256] f16
  _Float16* x0 = (_Float16*)((char*)d_out + (size_t)N * 512);  // [N][128] f16

  // CSR build
  int nzb = (N + 255) / 256;
  k_zero<<<nzb, 256, 0, stream>>>(deg, N);
  k_zero<<<nzb, 256, 0, stream>>>(cursor, N);
  k_deg<<<(E + 255) / 256, 256, 0, stream>>>(ei, deg, E);
  int nb = (N + 1023) / 1024;
  k_chunk_sum<<<nb, 256, 0, stream>>>(deg, bsum, N);
  k_scan_bsum<<<1, 64, 0, stream>>>(bsum, nb);
  k_scan_final<<<nb, 256, 0, stream>>>(deg, bsum, rs, dinv, N, E);
  k_fill<<<(E + 255) / 256, 256, 0, stream>>>(ei, rs, cursor, srcs, dsts, E);

  // casts
  k_cast_f16<<<((N * 128 / 4) + 255) / 256, 256, 0, stream>>>(feat, x0, N * 128 / 4);
  for (int l = 0; l < 3; l++) {
    int n4 = 256 * din[l] / 4;
    k_cast_f16<<<(n4 + 255) / 256, 256, 0, stream>>>(Wl[l], wlh[l], n4);
    k_cast_f16<<<(n4 + 255) / 256, 256, 0, stream>>>(Wr[l], wrh[l], n4);
  }

  int grid = (N + 63) / 64;
  k_fused<128, false><<<grid, 256, 0, stream>>>(x0, srcs, dsts, rs, dinv, wlh[0], wrh[0], Bv[0],
                                                y0, nullptr, N);
  k_fused<256, false><<<grid, 256, 0, stream>>>(y0, srcs, dsts, rs, dinv, wlh[1], wrh[1], Bv[1],
                                                xbuf, nullptr, N);
  k_fused<256, true><<<grid, 256, 0, stream>>>(xbuf, srcs, dsts, rs, dinv, wlh[2], wrh[2], Bv[2],
                                               nullptr, (float*)d_out, N);
}

// Round 7
// 1007.998 us; speedup vs baseline: 6.0497x; 6.0497x over previous
//
#include <hip/hip_runtime.h>
#include <hip/hip_bf16.h>
#include <type_traits>

typedef _Float16 half8_t __attribute__((ext_vector_type(8)));
typedef _Float16 half4_t __attribute__((ext_vector_type(4)));
typedef _Float16 half2_t __attribute__((ext_vector_type(2)));
typedef float f32x4 __attribute__((ext_vector_type(4)));

// ---------------- CSR build ----------------
// harness delivers integer inputs as int32 (edge_index int64 -> const int*).

static __global__ __launch_bounds__(256) void k_zero(int* __restrict__ a, int n) {
  int i = blockIdx.x * 256 + threadIdx.x;
  if (i < n) a[i] = 0;
}

static __global__ __launch_bounds__(256) void k_deg(const int* __restrict__ ei,
                                                    int* __restrict__ deg, int E) {
  int e = blockIdx.x * 256 + threadIdx.x;
  if (e < E) atomicAdd(&deg[ei[E + e]], 1);  // dst = ei[1][e]
}

static __global__ __launch_bounds__(256) void k_chunk_sum(const int* __restrict__ deg,
                                                          int* __restrict__ bsum, int n) {
  int t = threadIdx.x;
  int base = blockIdx.x * 1024 + t * 4;
  int s = 0;
#pragma unroll
  for (int j = 0; j < 4; j++) {
    int idx = base + j;
    if (idx < n) s += deg[idx];
  }
  __shared__ int red[256];
  red[t] = s;
  __syncthreads();
  for (int off = 128; off > 0; off >>= 1) {
    if (t < off) red[t] += red[t + off];
    __syncthreads();
  }
  if (t == 0) bsum[blockIdx.x] = red[0];
}

static __global__ void k_scan_bsum(int* bsum, int nb) {
  if (threadIdx.x == 0 && blockIdx.x == 0) {
    int run = 0;
    for (int i = 0; i < nb; i++) {
      int v = bsum[i];
      bsum[i] = run;
      run += v;
    }
  }
}

static __global__ __launch_bounds__(256) void k_scan_final(const int* __restrict__ deg,
                                                           const int* __restrict__ bsum,
                                                           int* __restrict__ rs,
                                                           float* __restrict__ dinv,
                                                           int n, int Etot) {
  int t = threadIdx.x;
  int base = blockIdx.x * 1024 + t * 4;
  int v[4];
  int s = 0;
#pragma unroll
  for (int j = 0; j < 4; j++) {
    int idx = base + j;
    v[j] = (idx < n) ? deg[idx] : 0;
    s += v[j];
  }
  __shared__ int sc[256];
  sc[t] = s;
  __syncthreads();
  for (int off = 1; off < 256; off <<= 1) {
    int add = (t >= off) ? sc[t - off] : 0;
    __syncthreads();
    sc[t] += add;
    __syncthreads();
  }
  int run = sc[t] - s + bsum[blockIdx.x];
#pragma unroll
  for (int j = 0; j < 4; j++) {
    int idx = base + j;
    if (idx < n) {
      rs[idx] = run;
      dinv[idx] = v[j] > 0 ? 1.0f / (float)v[j] : 0.0f;
      run += v[j];
    }
  }
  if (blockIdx.x == 0 && t == 0) rs[n] = Etot;
}

static __global__ __launch_bounds__(256) void k_fill(const int* __restrict__ ei,
                                                     const int* __restrict__ rs,
                                                     int* __restrict__ cursor,
                                                     int* __restrict__ srcs, int E) {
  int e = blockIdx.x * 256 + threadIdx.x;
  if (e < E) {
    int d = ei[E + e];
    int s = ei[e];
    int pos = atomicAdd(&cursor[d], 1);
    srcs[rs[d] + pos] = s;
  }
}

// ---------------- casts ----------------

static __global__ __launch_bounds__(256) void k_cast_f16(const float* __restrict__ in,
                                                         _Float16* __restrict__ out, int n4) {
  int i = blockIdx.x * 256 + threadIdx.x;
  if (i < n4) {
    float4 v = reinterpret_cast<const float4*>(in)[i];
    half4_t h;
    h[0] = (_Float16)v.x;
    h[1] = (_Float16)v.y;
    h[2] = (_Float16)v.z;
    h[3] = (_Float16)v.w;
    reinterpret_cast<half4_t*>(out)[i] = h;
  }
}

// ---------------- fused layer: mean-agg (registers -> LDS) + dual GEMM + bias + relu ------
// Block: 256 threads = 4 waves, owns 64 dst rows. Wave w aggregates nodes w*16..w*16+15.
// Phase 1 per node: predicated unroll-8 edge loop — always issue 8 row-loads (index
//   clamped to e1-1), accumulate under wave-uniform `if (e+k<e1)` (scalar branch).
//   8 rows x 512B = 4KB outstanding per wave; no atomics, no scalar tail.
// Phase 2: out[i][o] = relu(b[o] + mean[i]·Wl[o] + x[i]·Wr[o]); A(mean) from swizzled
//   LDS f16 tile, A(x) + B from global (weights L2-resident).

template <int DIN, bool LAST>
static __global__ __launch_bounds__(256) void k_fused(const _Float16* __restrict__ x,
                                                      const int* __restrict__ srcs,
                                                      const int* __restrict__ rs,
                                                      const float* __restrict__ dinv,
                                                      const _Float16* __restrict__ wl,
                                                      const _Float16* __restrict__ wr,
                                                      const float* __restrict__ bias,
                                                      _Float16* __restrict__ yout,
                                                      float* __restrict__ fout, int n) {
  constexpr int EPL = DIN / 64;  // f16 elems per lane per row
  using hv = typename std::conditional<EPL == 2, half2_t, half4_t>::type;
  __shared__ _Float16 meanT[64 * DIN];
  int lane = threadIdx.x & 63;
  int w = threadIdx.x >> 6;
  int i0 = blockIdx.x * 64;
  int co = lane * EPL;

  // ---- phase 1: mean aggregation, predicated unroll-8 ----
  for (int q = 0; q < 16; ++q) {
    int li = w * 16 + q;
    int i = i0 + li;
    float acc[EPL];
#pragma unroll
    for (int j = 0; j < EPL; j++) acc[j] = 0.0f;
    if (i < n) {
      int e0 = rs[i], e1 = rs[i + 1];
      for (int e = e0; e < e1; e += 8) {
        hv v[8];
#pragma unroll
        for (int k = 0; k < 8; k++) {
          int ee = e + k;
          ee = ee < e1 ? ee : e1 - 1;  // clamp (loop entered => e1-1 >= e0 valid)
          int s = srcs[ee];
          v[k] = *(const hv*)(x + (size_t)s * DIN + co);
        }
#pragma unroll
        for (int k = 0; k < 8; k++) {
          if (e + k < e1) {  // wave-uniform predicate
#pragma unroll
            for (int j = 0; j < EPL; j++) acc[j] += (float)v[k][j];
          }
        }
      }
      float di = dinv[i];
#pragma unroll
      for (int j = 0; j < EPL; j++) acc[j] *= di;
    }
    // swizzled LDS write (element-index XOR of bits 3..6; accesses stay in 8-elem units)
    unsigned idx = (unsigned)li * DIN + co;
    idx ^= ((li & 15) << 3);
    hv o;
#pragma unroll
    for (int j = 0; j < EPL; j++) o[j] = (_Float16)acc[j];
    *(hv*)&meanT[idx] = o;
  }
  __syncthreads();

  // ---- phase 2: dual GEMM ----
  int lr = lane & 15;
  int kq = lane >> 4;
  int n0 = w * 64;
  f32x4 acc2[4][4];
#pragma unroll
  for (int m = 0; m < 4; m++)
#pragma unroll
    for (int nn = 0; nn < 4; nn++) acc2[m][nn] = (f32x4)0.0f;

#pragma unroll 2
  for (int ks = 0; ks < DIN / 16; ++ks) {  // 2*DIN/32 k-steps
    int k0 = ks * 32;
    half8_t a[4], b[4];
    if (k0 < DIN) {
      // A = mean tile from LDS (swizzled)
#pragma unroll
      for (int m = 0; m < 4; m++) {
        int r = m * 16 + lr;
        unsigned idx = (unsigned)r * DIN + k0 + kq * 8;
        idx ^= ((r & 15) << 3);
        a[m] = *(const half8_t*)&meanT[idx];
      }
#pragma unroll
      for (int nn = 0; nn < 4; nn++) {
        int col = n0 + nn * 16 + lr;
        b[nn] = *(const half8_t*)(wl + (size_t)col * DIN + k0 + kq * 8);
      }
    } else {
      int kk = k0 - DIN;
#pragma unroll
      for (int m = 0; m < 4; m++) {
        int row = i0 + m * 16 + lr;
        if (row >= n) row = n - 1;  // clamp; stores guarded
        a[m] = *(const half8_t*)(x + (size_t)row * DIN + kk + kq * 8);
      }
#pragma unroll
      for (int nn = 0; nn < 4; nn++) {
        int col = n0 + nn * 16 + lr;
        b[nn] = *(const half8_t*)(wr + (size_t)col * DIN + kk + kq * 8);
      }
    }
#pragma unroll
    for (int m = 0; m < 4; m++)
#pragma unroll
      for (int nn = 0; nn < 4; nn++)
        acc2[m][nn] = __builtin_amdgcn_mfma_f32_16x16x32_f16(a[m], b[nn], acc2[m][nn], 0, 0, 0);
  }

  // ---- epilogue ----
#pragma unroll
  for (int nn = 0; nn < 4; nn++) {
    int col = n0 + nn * 16 + lr;  // D col = lane&15
    float bv = bias[col];
#pragma unroll
    for (int m = 0; m < 4; m++) {
#pragma unroll
      for (int r = 0; r < 4; r++) {
        int row = i0 + m * 16 + kq * 4 + r;  // D row = (lane>>4)*4 + r
        if (row < n) {
          float v = acc2[m][nn][r] + bv;
          v = v > 0.0f ? v : 0.0f;
          if constexpr (LAST)
            fout[(size_t)row * 256 + col] = v;
          else
            yout[(size_t)row * 256 + col] = (_Float16)v;
        }
      }
    }
  }
}

// ---------------- host launch ----------------
// ws  : xbuf(51.2M) srcs(6.4M) rs deg cursor dinv bsum weights(f16)  ~= 61 MB (proven safe)
// dout: [0,51.2M) y0 f16 (L0 out); [51.2M,76.8M) x0 f16 (feature cast);
//       final fused layer reads only ws (xbuf) and writes full d_out f32 last.

extern "C" void kernel_launch(void* const* d_in, const int* in_sizes, int n_in,
                              void* d_out, int out_size, void* d_ws, size_t ws_size,
                              hipStream_t stream) {
  const float* feat = (const float*)d_in[0];
  const int* ei = (const int*)d_in[1];
  const float* Wl[3] = {(const float*)d_in[2], (const float*)d_in[5], (const float*)d_in[8]};
  const float* Wr[3] = {(const float*)d_in[3], (const float*)d_in[6], (const float*)d_in[9]};
  const float* Bv[3] = {(const float*)d_in[4], (const float*)d_in[7], (const float*)d_in[10]};
  int N = in_sizes[0] / 128;
  int E = in_sizes[1] / 2;

  char* p = (char*)d_ws;
  auto carve = [&](size_t bytes) {
    char* r = p;
    p += (bytes + 255) & ~(size_t)255;
    return r;
  };
  _Float16* xbuf = (_Float16*)carve((size_t)N * 256 * 2);  // layer-1 output
  int* srcs = (int*)carve((size_t)E * 4);
  int* rs = (int*)carve((size_t)(N + 1) * 4);
  int* deg = (int*)carve((size_t)N * 4);
  int* cursor = (int*)carve((size_t)N * 4);
  float* dinv = (float*)carve((size_t)N * 4);
  int* bsum = (int*)carve(4096);
  const int din[3] = {128, 256, 256};
  _Float16* wlh[3];
  _Float16* wrh[3];
  for (int l = 0; l < 3; l++) {
    wlh[l] = (_Float16*)carve((size_t)256 * din[l] * 2);
    wrh[l] = (_Float16*)carve((size_t)256 * din[l] * 2);
  }

  _Float16* y0 = (_Float16*)d_out;                             // [N][256] f16
  _Float16* x0 = (_Float16*)((char*)d_out + (size_t)N * 512);  // [N][128] f16

  // CSR build
  int nzb = (N + 255) / 256;
  k_zero<<<nzb, 256, 0, stream>>>(deg, N);
  k_zero<<<nzb, 256, 0, stream>>>(cursor, N);
  k_deg<<<(E + 255) / 256, 256, 0, stream>>>(ei, deg, E);
  int nb = (N + 1023) / 1024;
  k_chunk_sum<<<nb, 256, 0, stream>>>(deg, bsum, N);
  k_scan_bsum<<<1, 64, 0, stream>>>(bsum, nb);
  k_scan_final<<<nb, 256, 0, stream>>>(deg, bsum, rs, dinv, N, E);
  k_fill<<<(E + 255) / 256, 256, 0, stream>>>(ei, rs, cursor, srcs, E);

  // casts
  k_cast_f16<<<((N * 128 / 4) + 255) / 256, 256, 0, stream>>>(feat, x0, N * 128 / 4);
  for (int l = 0; l < 3; l++) {
    int n4 = 256 * din[l] / 4;
    k_cast_f16<<<(n4 + 255) / 256, 256, 0, stream>>>(Wl[l], wlh[l], n4);
    k_cast_f16<<<(n4 + 255) / 256, 256, 0, stream>>>(Wr[l], wrh[l], n4);
  }

  int grid = (N + 63) / 64;
  k_fused<128, false><<<grid, 256, 0, stream>>>(x0, srcs, rs, dinv, wlh[0], wrh[0], Bv[0], y0,
                                                nullptr, N);
  k_fused<256, false><<<grid, 256, 0, stream>>>(y0, srcs, rs, dinv, wlh[1], wrh[1], Bv[1], xbuf,
                                                nullptr, N);
  k_fused<256, true><<<grid, 256, 0, stream>>>(xbuf, srcs, rs, dinv, wlh[2], wrh[2], Bv[2], nullptr,
                                               (float*)d_out, N);
}

// Round 8
// 898.252 us; speedup vs baseline: 6.7889x; 1.1222x over previous
//
#include <hip/hip_runtime.h>
#include <hip/hip_bf16.h>
#include <type_traits>

typedef _Float16 half8_t __attribute__((ext_vector_type(8)));
typedef _Float16 half4_t __attribute__((ext_vector_type(4)));
typedef _Float16 half2_t __attribute__((ext_vector_type(2)));
typedef float f32x4 __attribute__((ext_vector_type(4)));

// ---------------- CSR build ----------------
// harness delivers integer inputs as int32 (edge_index int64 -> const int*).

static __global__ __launch_bounds__(256) void k_zero(int* __restrict__ a, int n) {
  int i = blockIdx.x * 256 + threadIdx.x;
  if (i < n) a[i] = 0;
}

static __global__ __launch_bounds__(256) void k_deg(const int* __restrict__ ei,
                                                    int* __restrict__ deg, int E) {
  int e = blockIdx.x * 256 + threadIdx.x;
  if (e < E) atomicAdd(&deg[ei[E + e]], 1);  // dst = ei[1][e]
}

static __global__ __launch_bounds__(256) void k_chunk_sum(const int* __restrict__ deg,
                                                          int* __restrict__ bsum, int n) {
  int t = threadIdx.x;
  int base = blockIdx.x * 1024 + t * 4;
  int s = 0;
#pragma unroll
  for (int j = 0; j < 4; j++) {
    int idx = base + j;
    if (idx < n) s += deg[idx];
  }
  __shared__ int red[256];
  red[t] = s;
  __syncthreads();
  for (int off = 128; off > 0; off >>= 1) {
    if (t < off) red[t] += red[t + off];
    __syncthreads();
  }
  if (t == 0) bsum[blockIdx.x] = red[0];
}

static __global__ void k_scan_bsum(int* bsum, int nb) {
  if (threadIdx.x == 0 && blockIdx.x == 0) {
    int run = 0;
    for (int i = 0; i < nb; i++) {
      int v = bsum[i];
      bsum[i] = run;
      run += v;
    }
  }
}

static __global__ __launch_bounds__(256) void k_scan_final(const int* __restrict__ deg,
                                                           const int* __restrict__ bsum,
                                                           int* __restrict__ rs,
                                                           float* __restrict__ dinv,
                                                           int n, int Etot) {
  int t = threadIdx.x;
  int base = blockIdx.x * 1024 + t * 4;
  int v[4];
  int s = 0;
#pragma unroll
  for (int j = 0; j < 4; j++) {
    int idx = base + j;
    v[j] = (idx < n) ? deg[idx] : 0;
    s += v[j];
  }
  __shared__ int sc[256];
  sc[t] = s;
  __syncthreads();
  for (int off = 1; off < 256; off <<= 1) {
    int add = (t >= off) ? sc[t - off] : 0;
    __syncthreads();
    sc[t] += add;
    __syncthreads();
  }
  int run = sc[t] - s + bsum[blockIdx.x];
#pragma unroll
  for (int j = 0; j < 4; j++) {
    int idx = base + j;
    if (idx < n) {
      rs[idx] = run;
      dinv[idx] = v[j] > 0 ? 1.0f / (float)v[j] : 0.0f;
      run += v[j];
    }
  }
  if (blockIdx.x == 0 && t == 0) rs[n] = Etot;
}

static __global__ __launch_bounds__(256) void k_fill(const int* __restrict__ ei,
                                                     const int* __restrict__ rs,
                                                     int* __restrict__ cursor,
                                                     int* __restrict__ srcs, int E) {
  int e = blockIdx.x * 256 + threadIdx.x;
  if (e < E) {
    int d = ei[E + e];
    int s = ei[e];
    int pos = atomicAdd(&cursor[d], 1);
    srcs[rs[d] + pos] = s;
  }
}

// ---------------- casts ----------------

static __global__ __launch_bounds__(256) void k_cast_f16(const float* __restrict__ in,
                                                         _Float16* __restrict__ out, int n4) {
  int i = blockIdx.x * 256 + threadIdx.x;
  if (i < n4) {
    float4 v = reinterpret_cast<const float4*>(in)[i];
    half4_t h;
    h[0] = (_Float16)v.x;
    h[1] = (_Float16)v.y;
    h[2] = (_Float16)v.z;
    h[3] = (_Float16)v.w;
    reinterpret_cast<half4_t*>(out)[i] = h;
  }
}

// ---------------- high-occupancy mean aggregation ----------------
// 1 wave per dst node, no LDS, no AGPRs (target <=64 VGPR -> 8 waves/SIMD).
// Same 8-deep predicated inner loop as round 7 (only the occupancy regime changes).

template <int DIN>
static __global__ __launch_bounds__(256) void k_aggm(const _Float16* __restrict__ x,
                                                     const int* __restrict__ srcs,
                                                     const int* __restrict__ rs,
                                                     const float* __restrict__ dinv,
                                                     _Float16* __restrict__ meanb, int n) {
  constexpr int EPL = DIN / 64;
  using hv = typename std::conditional<EPL == 2, half2_t, half4_t>::type;
  int lane = threadIdx.x & 63;
  int w = threadIdx.x >> 6;
  int i = blockIdx.x * 4 + w;
  if (i >= n) return;
  int e0 = rs[i], e1 = rs[i + 1];
  int co = lane * EPL;
  float acc[EPL];
#pragma unroll
  for (int j = 0; j < EPL; j++) acc[j] = 0.0f;
  for (int e = e0; e < e1; e += 8) {
    hv v[8];
#pragma unroll
    for (int k = 0; k < 8; k++) {
      int ee = e + k;
      ee = ee < e1 ? ee : e1 - 1;  // clamp (loop entered => e1-1 >= e0)
      v[k] = *(const hv*)(x + (size_t)srcs[ee] * DIN + co);
    }
#pragma unroll
    for (int k = 0; k < 8; k++) {
      if (e + k < e1) {  // wave-uniform predicate
#pragma unroll
        for (int j = 0; j < EPL; j++) acc[j] += (float)v[k][j];
      }
    }
  }
  float di = dinv[i];
  hv o;
#pragma unroll
  for (int j = 0; j < EPL; j++) o[j] = (_Float16)(acc[j] * di);
  *(hv*)(meanb + (size_t)i * DIN + co) = o;
}

// ---------------- dual GEMM + bias + relu (direct-global, round-1 proven) ----------------

template <int K2, int DIN, bool LAST>
static __global__ __launch_bounds__(256) void k_gemm(const _Float16* __restrict__ meanb,
                                                     const _Float16* __restrict__ xb,
                                                     const _Float16* __restrict__ wlh,
                                                     const _Float16* __restrict__ wrh,
                                                     const float* __restrict__ bias,
                                                     _Float16* __restrict__ yout,
                                                     float* __restrict__ fout, int M) {
  int lane = threadIdx.x & 63;
  int w = threadIdx.x >> 6;
  int i0 = blockIdx.x * 64;
  int n0 = w * 64;
  int lr = lane & 15;
  int kq = lane >> 4;
  f32x4 acc[4][4];
#pragma unroll
  for (int m = 0; m < 4; m++)
#pragma unroll
    for (int n = 0; n < 4; n++) acc[m][n] = (f32x4)0.0f;

#pragma unroll 2
  for (int ks = 0; ks < K2 / 32; ++ks) {
    int k0 = ks * 32;
    const _Float16* Ab;
    const _Float16* Bb;
    if (k0 < DIN) {
      Ab = meanb + k0;
      Bb = wlh + k0;
    } else {
      Ab = xb + (k0 - DIN);
      Bb = wrh + (k0 - DIN);
    }
    half8_t a[4], b[4];
#pragma unroll
    for (int m = 0; m < 4; m++) {
      int row = i0 + m * 16 + lr;
      if (row >= M) row = M - 1;  // clamp (stores are guarded)
      a[m] = *(const half8_t*)(Ab + (size_t)row * DIN + kq * 8);
    }
#pragma unroll
    for (int n = 0; n < 4; n++) {
      int col = n0 + n * 16 + lr;
      b[n] = *(const half8_t*)(Bb + (size_t)col * DIN + kq * 8);
    }
#pragma unroll
    for (int m = 0; m < 4; m++)
#pragma unroll
      for (int n = 0; n < 4; n++)
        acc[m][n] = __builtin_amdgcn_mfma_f32_16x16x32_f16(a[m], b[n], acc[m][n], 0, 0, 0);
  }

#pragma unroll
  for (int n = 0; n < 4; n++) {
    int col = n0 + n * 16 + lr;  // D col = lane&15
    float bv = bias[col];
#pragma unroll
    for (int m = 0; m < 4; m++) {
#pragma unroll
      for (int r = 0; r < 4; r++) {
        int row = i0 + m * 16 + kq * 4 + r;  // D row = (lane>>4)*4 + r
        if (row < M) {
          float v = acc[m][n][r] + bv;
          v = v > 0.0f ? v : 0.0f;
          if constexpr (LAST)
            fout[(size_t)row * 256 + col] = v;
          else
            yout[(size_t)row * 256 + col] = (_Float16)v;
        }
      }
    }
  }
}

// ---------------- fused layer (kept for layer 2 only) ----------------

template <int DIN, bool LAST>
static __global__ __launch_bounds__(256) void k_fused(const _Float16* __restrict__ x,
                                                      const int* __restrict__ srcs,
                                                      const int* __restrict__ rs,
                                                      const float* __restrict__ dinv,
                                                      const _Float16* __restrict__ wl,
                                                      const _Float16* __restrict__ wr,
                                                      const float* __restrict__ bias,
                                                      _Float16* __restrict__ yout,
                                                      float* __restrict__ fout, int n) {
  constexpr int EPL = DIN / 64;
  using hv = typename std::conditional<EPL == 2, half2_t, half4_t>::type;
  __shared__ _Float16 meanT[64 * DIN];
  int lane = threadIdx.x & 63;
  int w = threadIdx.x >> 6;
  int i0 = blockIdx.x * 64;
  int co = lane * EPL;

  for (int q = 0; q < 16; ++q) {
    int li = w * 16 + q;
    int i = i0 + li;
    float acc[EPL];
#pragma unroll
    for (int j = 0; j < EPL; j++) acc[j] = 0.0f;
    if (i < n) {
      int e0 = rs[i], e1 = rs[i + 1];
      for (int e = e0; e < e1; e += 8) {
        hv v[8];
#pragma unroll
        for (int k = 0; k < 8; k++) {
          int ee = e + k;
          ee = ee < e1 ? ee : e1 - 1;
          v[k] = *(const hv*)(x + (size_t)srcs[ee] * DIN + co);
        }
#pragma unroll
        for (int k = 0; k < 8; k++) {
          if (e + k < e1) {
#pragma unroll
            for (int j = 0; j < EPL; j++) acc[j] += (float)v[k][j];
          }
        }
      }
      float di = dinv[i];
#pragma unroll
      for (int j = 0; j < EPL; j++) acc[j] *= di;
    }
    unsigned idx = (unsigned)li * DIN + co;
    idx ^= ((li & 15) << 3);
    hv o;
#pragma unroll
    for (int j = 0; j < EPL; j++) o[j] = (_Float16)acc[j];
    *(hv*)&meanT[idx] = o;
  }
  __syncthreads();

  int lr = lane & 15;
  int kq = lane >> 4;
  int n0 = w * 64;
  f32x4 acc2[4][4];
#pragma unroll
  for (int m = 0; m < 4; m++)
#pragma unroll
    for (int nn = 0; nn < 4; nn++) acc2[m][nn] = (f32x4)0.0f;

#pragma unroll 2
  for (int ks = 0; ks < DIN / 16; ++ks) {
    int k0 = ks * 32;
    half8_t a[4], b[4];
    if (k0 < DIN) {
#pragma unroll
      for (int m = 0; m < 4; m++) {
        int r = m * 16 + lr;
        unsigned idx = (unsigned)r * DIN + k0 + kq * 8;
        idx ^= ((r & 15) << 3);
        a[m] = *(const half8_t*)&meanT[idx];
      }
#pragma unroll
      for (int nn = 0; nn < 4; nn++) {
        int col = n0 + nn * 16 + lr;
        b[nn] = *(const half8_t*)(wl + (size_t)col * DIN + k0 + kq * 8);
      }
    } else {
      int kk = k0 - DIN;
#pragma unroll
      for (int m = 0; m < 4; m++) {
        int row = i0 + m * 16 + lr;
        if (row >= n) row = n - 1;
        a[m] = *(const half8_t*)(x + (size_t)row * DIN + kk + kq * 8);
      }
#pragma unroll
      for (int nn = 0; nn < 4; nn++) {
        int col = n0 + nn * 16 + lr;
        b[nn] = *(const half8_t*)(wr + (size_t)col * DIN + kk + kq * 8);
      }
    }
#pragma unroll
    for (int m = 0; m < 4; m++)
#pragma unroll
      for (int nn = 0; nn < 4; nn++)
        acc2[m][nn] = __builtin_amdgcn_mfma_f32_16x16x32_f16(a[m], b[nn], acc2[m][nn], 0, 0, 0);
  }

#pragma unroll
  for (int nn = 0; nn < 4; nn++) {
    int col = n0 + nn * 16 + lr;
    float bv = bias[col];
#pragma unroll
    for (int m = 0; m < 4; m++) {
#pragma unroll
      for (int r = 0; r < 4; r++) {
        int row = i0 + m * 16 + kq * 4 + r;
        if (row < n) {
          float v = acc2[m][nn][r] + bv;
          v = v > 0.0f ? v : 0.0f;
          if constexpr (LAST)
            fout[(size_t)row * 256 + col] = v;
          else
            yout[(size_t)row * 256 + col] = (_Float16)v;
        }
      }
    }
  }
}

// ---------------- host launch ----------------
// ws (61 MB, proven safe): xbuf(51.2M)=x1  srcs(6.4M) rs deg cursor dinv bsum weights(f16)
// d_out (N*1024 B) timeline per call:
//   bytes [0,512N)      : y0 f16  (written by gemm0, read by agg1/gemm1, dead after)
//   bytes [512N,768N)   : x0 f16  (cast; read by agg0/gemm0, dead after)
//   bytes [768N,1024N)  : mean0 f16 [N][128] (agg0 -> gemm0, dead after)
//   bytes [512N,1024N)  : mean1 f16 [N][256] (agg1 -> gemm1; overwrites dead x0/mean0)
//   final: k_fused<256,true> reads ONLY ws (xbuf,srcs,rs,dinv,weights) and writes
//          the full f32 output over d_out (y0/mean1 dead by then). All regions are
//          rewritten before being read on every call (no cross-call state).

extern "C" void kernel_launch(void* const* d_in, const int* in_sizes, int n_in,
                              void* d_out, int out_size, void* d_ws, size_t ws_size,
                              hipStream_t stream) {
  const float* feat = (const float*)d_in[0];
  const int* ei = (const int*)d_in[1];
  const float* Wl[3] = {(const float*)d_in[2], (const float*)d_in[5], (const float*)d_in[8]};
  const float* Wr[3] = {(const float*)d_in[3], (const float*)d_in[6], (const float*)d_in[9]};
  const float* Bv[3] = {(const float*)d_in[4], (const float*)d_in[7], (const float*)d_in[10]};
  int N = in_sizes[0] / 128;
  int E = in_sizes[1] / 2;

  char* p = (char*)d_ws;
  auto carve = [&](size_t bytes) {
    char* r = p;
    p += (bytes + 255) & ~(size_t)255;
    return r;
  };
  _Float16* xbuf = (_Float16*)carve((size_t)N * 256 * 2);  // x1 = layer-1 output
  int* srcs = (int*)carve((size_t)E * 4);
  int* rs = (int*)carve((size_t)(N + 1) * 4);
  int* deg = (int*)carve((size_t)N * 4);
  int* cursor = (int*)carve((size_t)N * 4);
  float* dinv = (float*)carve((size_t)N * 4);
  int* bsum = (int*)carve(4096);
  const int din[3] = {128, 256, 256};
  _Float16* wlh[3];
  _Float16* wrh[3];
  for (int l = 0; l < 3; l++) {
    wlh[l] = (_Float16*)carve((size_t)256 * din[l] * 2);
    wrh[l] = (_Float16*)carve((size_t)256 * din[l] * 2);
  }

  _Float16* y0 = (_Float16*)d_out;                               // [N][256] f16
  _Float16* x0 = (_Float16*)((char*)d_out + (size_t)N * 512);    // [N][128] f16
  _Float16* mean0 = (_Float16*)((char*)d_out + (size_t)N * 768); // [N][128] f16
  _Float16* mean1 = (_Float16*)((char*)d_out + (size_t)N * 512); // [N][256] f16

  // CSR build
  int nzb = (N + 255) / 256;
  k_zero<<<nzb, 256, 0, stream>>>(deg, N);
  k_zero<<<nzb, 256, 0, stream>>>(cursor, N);
  k_deg<<<(E + 255) / 256, 256, 0, stream>>>(ei, deg, E);
  int nb = (N + 1023) / 1024;
  k_chunk_sum<<<nb, 256, 0, stream>>>(deg, bsum, N);
  k_scan_bsum<<<1, 64, 0, stream>>>(bsum, nb);
  k_scan_final<<<nb, 256, 0, stream>>>(deg, bsum, rs, dinv, N, E);
  k_fill<<<(E + 255) / 256, 256, 0, stream>>>(ei, rs, cursor, srcs, E);

  // casts
  k_cast_f16<<<((N * 128 / 4) + 255) / 256, 256, 0, stream>>>(feat, x0, N * 128 / 4);
  for (int l = 0; l < 3; l++) {
    int n4 = 256 * din[l] / 4;
    k_cast_f16<<<(n4 + 255) / 256, 256, 0, stream>>>(Wl[l], wlh[l], n4);
    k_cast_f16<<<(n4 + 255) / 256, 256, 0, stream>>>(Wr[l], wrh[l], n4);
  }

  int aggGrid = (N + 3) / 4;
  int gemmGrid = (N + 63) / 64;

  // Layer 0 (de-fused): agg -> mean0, gemm -> y0
  k_aggm<128><<<aggGrid, 256, 0, stream>>>(x0, srcs, rs, dinv, mean0, N);
  k_gemm<256, 128, false><<<gemmGrid, 256, 0, stream>>>(mean0, x0, wlh[0], wrh[0], Bv[0], y0,
                                                        nullptr, N);
  // Layer 1 (de-fused): agg -> mean1 (over dead x0/mean0), gemm -> x1 (ws)
  k_aggm<256><<<aggGrid, 256, 0, stream>>>(y0, srcs, rs, dinv, mean1, N);
  k_gemm<512, 256, false><<<gemmGrid, 256, 0, stream>>>(mean1, y0, wlh[1], wrh[1], Bv[1], xbuf,
                                                        nullptr, N);
  // Layer 2 (fused): reads only ws, writes full f32 d_out
  k_fused<256, true><<<gemmGrid, 256, 0, stream>>>(xbuf, srcs, rs, dinv, wlh[2], wrh[2], Bv[2],
                                                   nullptr, (float*)d_out, N);
}

// Round 9
// 841.785 us; speedup vs baseline: 7.2443x; 1.0671x over previous
//
#include <hip/hip_runtime.h>
#include <hip/hip_bf16.h>
#include <type_traits>

typedef _Float16 half8_t __attribute__((ext_vector_type(8)));
typedef _Float16 half4_t __attribute__((ext_vector_type(4)));
typedef _Float16 half2_t __attribute__((ext_vector_type(2)));
typedef float f32x4 __attribute__((ext_vector_type(4)));

// ---------------- CSR build ----------------
// harness delivers integer inputs as int32 (edge_index int64 -> const int*).

static __global__ __launch_bounds__(256) void k_zero(int* __restrict__ a, int n) {
  int i = blockIdx.x * 256 + threadIdx.x;
  if (i < n) a[i] = 0;
}

static __global__ __launch_bounds__(256) void k_deg(const int* __restrict__ ei,
                                                    int* __restrict__ deg, int E) {
  int e = blockIdx.x * 256 + threadIdx.x;
  if (e < E) atomicAdd(&deg[ei[E + e]], 1);  // dst = ei[1][e]
}

static __global__ __launch_bounds__(256) void k_chunk_sum(const int* __restrict__ deg,
                                                          int* __restrict__ bsum, int n) {
  int t = threadIdx.x;
  int base = blockIdx.x * 1024 + t * 4;
  int s = 0;
#pragma unroll
  for (int j = 0; j < 4; j++) {
    int idx = base + j;
    if (idx < n) s += deg[idx];
  }
  __shared__ int red[256];
  red[t] = s;
  __syncthreads();
  for (int off = 128; off > 0; off >>= 1) {
    if (t < off) red[t] += red[t + off];
    __syncthreads();
  }
  if (t == 0) bsum[blockIdx.x] = red[0];
}

static __global__ void k_scan_bsum(int* bsum, int nb) {
  if (threadIdx.x == 0 && blockIdx.x == 0) {
    int run = 0;
    for (int i = 0; i < nb; i++) {
      int v = bsum[i];
      bsum[i] = run;
      run += v;
    }
  }
}

static __global__ __launch_bounds__(256) void k_scan_final(const int* __restrict__ deg,
                                                           const int* __restrict__ bsum,
                                                           int* __restrict__ rs,
                                                           float* __restrict__ dinv,
                                                           int n, int Etot) {
  int t = threadIdx.x;
  int base = blockIdx.x * 1024 + t * 4;
  int v[4];
  int s = 0;
#pragma unroll
  for (int j = 0; j < 4; j++) {
    int idx = base + j;
    v[j] = (idx < n) ? deg[idx] : 0;
    s += v[j];
  }
  __shared__ int sc[256];
  sc[t] = s;
  __syncthreads();
  for (int off = 1; off < 256; off <<= 1) {
    int add = (t >= off) ? sc[t - off] : 0;
    __syncthreads();
    sc[t] += add;
    __syncthreads();
  }
  int run = sc[t] - s + bsum[blockIdx.x];
#pragma unroll
  for (int j = 0; j < 4; j++) {
    int idx = base + j;
    if (idx < n) {
      rs[idx] = run;
      dinv[idx] = v[j] > 0 ? 1.0f / (float)v[j] : 0.0f;
      run += v[j];
    }
  }
  if (blockIdx.x == 0 && t == 0) rs[n] = Etot;
}

static __global__ __launch_bounds__(256) void k_fill(const int* __restrict__ ei,
                                                     const int* __restrict__ rs,
                                                     int* __restrict__ cursor,
                                                     int* __restrict__ srcs, int E) {
  int e = blockIdx.x * 256 + threadIdx.x;
  if (e < E) {
    int d = ei[E + e];
    int s = ei[e];
    int pos = atomicAdd(&cursor[d], 1);
    srcs[rs[d] + pos] = s;
  }
}

// ---------------- casts ----------------

static __global__ __launch_bounds__(256) void k_cast_f16(const float* __restrict__ in,
                                                         _Float16* __restrict__ out, int n4) {
  int i = blockIdx.x * 256 + threadIdx.x;
  if (i < n4) {
    float4 v = reinterpret_cast<const float4*>(in)[i];
    half4_t h;
    h[0] = (_Float16)v.x;
    h[1] = (_Float16)v.y;
    h[2] = (_Float16)v.z;
    h[3] = (_Float16)v.w;
    reinterpret_cast<half4_t*>(out)[i] = h;
  }
}

// ---------------- high-occupancy mean aggregation ----------------
// 1 wave per dst node, no LDS, no AGPRs. OSTR = output row pitch in f16 elems
// (512 for the interleaved layer-2 layout).

template <int DIN, int OSTR>
static __global__ __launch_bounds__(256) void k_aggm(const _Float16* __restrict__ x,
                                                     const int* __restrict__ srcs,
                                                     const int* __restrict__ rs,
                                                     const float* __restrict__ dinv,
                                                     _Float16* __restrict__ meanb, int n) {
  constexpr int EPL = DIN / 64;
  using hv = typename std::conditional<EPL == 2, half2_t, half4_t>::type;
  int lane = threadIdx.x & 63;
  int w = threadIdx.x >> 6;
  int i = blockIdx.x * 4 + w;
  if (i >= n) return;
  int e0 = rs[i], e1 = rs[i + 1];
  int co = lane * EPL;
  float acc[EPL];
#pragma unroll
  for (int j = 0; j < EPL; j++) acc[j] = 0.0f;
  for (int e = e0; e < e1; e += 8) {
    hv v[8];
#pragma unroll
    for (int k = 0; k < 8; k++) {
      int ee = e + k;
      ee = ee < e1 ? ee : e1 - 1;  // clamp (loop entered => e1-1 >= e0)
      v[k] = *(const hv*)(x + (size_t)srcs[ee] * DIN + co);
    }
#pragma unroll
    for (int k = 0; k < 8; k++) {
      if (e + k < e1) {  // wave-uniform predicate
#pragma unroll
        for (int j = 0; j < EPL; j++) acc[j] += (float)v[k][j];
      }
    }
  }
  float di = dinv[i];
  hv o;
#pragma unroll
  for (int j = 0; j < EPL; j++) o[j] = (_Float16)(acc[j] * di);
  *(hv*)(meanb + (size_t)i * OSTR + co) = o;
}

// ---------------- dual GEMM + bias + relu (direct-global) ----------------
// ASTR = mean row pitch in f16 elems. For LAST (in-place over interleaved mean2 in
// d_out): A-reads are block-local rows [i0,i0+64) and the f32 stores cover exactly
// those rows; __syncthreads() between K-loop and epilogue orders all waves' loads
// before any store (same CU/L2 -> coherent).

template <int K2, int DIN, int ASTR, bool LAST>
static __global__ __launch_bounds__(256) void k_gemm(const _Float16* __restrict__ meanb,
                                                     const _Float16* __restrict__ xb,
                                                     const _Float16* __restrict__ wlh,
                                                     const _Float16* __restrict__ wrh,
                                                     const float* __restrict__ bias,
                                                     _Float16* __restrict__ yout,
                                                     float* __restrict__ fout, int M) {
  int lane = threadIdx.x & 63;
  int w = threadIdx.x >> 6;
  int i0 = blockIdx.x * 64;
  int n0 = w * 64;
  int lr = lane & 15;
  int kq = lane >> 4;
  f32x4 acc[4][4];
#pragma unroll
  for (int m = 0; m < 4; m++)
#pragma unroll
    for (int n = 0; n < 4; n++) acc[m][n] = (f32x4)0.0f;

#pragma unroll 2
  for (int ks = 0; ks < K2 / 32; ++ks) {
    int k0 = ks * 32;
    half8_t a[4], b[4];
    if (k0 < DIN) {
#pragma unroll
      for (int m = 0; m < 4; m++) {
        int row = i0 + m * 16 + lr;
        if (row >= M) row = M - 1;  // clamp (stores are guarded)
        a[m] = *(const half8_t*)(meanb + (size_t)row * ASTR + k0 + kq * 8);
      }
#pragma unroll
      for (int n = 0; n < 4; n++) {
        int col = n0 + n * 16 + lr;
        b[n] = *(const half8_t*)(wlh + (size_t)col * DIN + k0 + kq * 8);
      }
    } else {
      int kk = k0 - DIN;
#pragma unroll
      for (int m = 0; m < 4; m++) {
        int row = i0 + m * 16 + lr;
        if (row >= M) row = M - 1;
        a[m] = *(const half8_t*)(xb + (size_t)row * DIN + kk + kq * 8);
      }
#pragma unroll
      for (int n = 0; n < 4; n++) {
        int col = n0 + n * 16 + lr;
        b[n] = *(const half8_t*)(wrh + (size_t)col * DIN + kk + kq * 8);
      }
    }
#pragma unroll
    for (int m = 0; m < 4; m++)
#pragma unroll
      for (int n = 0; n < 4; n++)
        acc[m][n] = __builtin_amdgcn_mfma_f32_16x16x32_f16(a[m], b[n], acc[m][n], 0, 0, 0);
  }

  if constexpr (LAST) __syncthreads();  // all A-loads done before in-place stores

#pragma unroll
  for (int n = 0; n < 4; n++) {
    int col = n0 + n * 16 + lr;  // D col = lane&15
    float bv = bias[col];
#pragma unroll
    for (int m = 0; m < 4; m++) {
#pragma unroll
      for (int r = 0; r < 4; r++) {
        int row = i0 + m * 16 + kq * 4 + r;  // D row = (lane>>4)*4 + r
        if (row < M) {
          float v = acc[m][n][r] + bv;
          v = v > 0.0f ? v : 0.0f;
          if constexpr (LAST)
            fout[(size_t)row * 256 + col] = v;
          else
            yout[(size_t)row * 256 + col] = (_Float16)v;
        }
      }
    }
  }
}

// ---------------- host launch ----------------
// ws (61 MB, proven safe): xbuf(51.2M)=x1  srcs(6.4M) rs deg cursor dinv bsum weights(f16)
// d_out (N*1024 B) timeline per call (every region written before read, no cross-call state):
//   cast:  x0 f16 [N][128] at bytes [512N,768N)
//   agg0:  mean0 f16 [N][128] at [768N,1024N)          (reads x0)
//   gemm0: y0 f16 [N][256] at [0,512N)                 (reads mean0,x0; disjoint)
//   agg1:  mean1 f16 [N][256] at [512N,1024N)          (reads y0; overwrites dead x0/mean0)
//   gemm1: x1 f16 -> ws.xbuf                           (reads mean1,y0)
//   agg2:  mean2 f16 [N][256] INTERLEAVED: row r = first 512B of each 1024B d_out row
//          (reads ws.xbuf only; overwrites dead y0/mean1)
//   gemm2: f32 [N][256] over all of d_out, in-place per block (reads mean2 rows
//          [i0,i0+64) + ws.xbuf; barrier before stores; no cross-block overlap)

extern "C" void kernel_launch(void* const* d_in, const int* in_sizes, int n_in,
                              void* d_out, int out_size, void* d_ws, size_t ws_size,
                              hipStream_t stream) {
  const float* feat = (const float*)d_in[0];
  const int* ei = (const int*)d_in[1];
  const float* Wl[3] = {(const float*)d_in[2], (const float*)d_in[5], (const float*)d_in[8]};
  const float* Wr[3] = {(const float*)d_in[3], (const float*)d_in[6], (const float*)d_in[9]};
  const float* Bv[3] = {(const float*)d_in[4], (const float*)d_in[7], (const float*)d_in[10]};
  int N = in_sizes[0] / 128;
  int E = in_sizes[1] / 2;

  char* p = (char*)d_ws;
  auto carve = [&](size_t bytes) {
    char* r = p;
    p += (bytes + 255) & ~(size_t)255;
    return r;
  };
  _Float16* xbuf = (_Float16*)carve((size_t)N * 256 * 2);  // x1 = layer-1 output
  int* srcs = (int*)carve((size_t)E * 4);
  int* rs = (int*)carve((size_t)(N + 1) * 4);
  int* deg = (int*)carve((size_t)N * 4);
  int* cursor = (int*)carve((size_t)N * 4);
  float* dinv = (float*)carve((size_t)N * 4);
  int* bsum = (int*)carve(4096);
  const int din[3] = {128, 256, 256};
  _Float16* wlh[3];
  _Float16* wrh[3];
  for (int l = 0; l < 3; l++) {
    wlh[l] = (_Float16*)carve((size_t)256 * din[l] * 2);
    wrh[l] = (_Float16*)carve((size_t)256 * din[l] * 2);
  }

  _Float16* y0 = (_Float16*)d_out;                               // [N][256] f16
  _Float16* x0 = (_Float16*)((char*)d_out + (size_t)N * 512);    // [N][128] f16
  _Float16* mean0 = (_Float16*)((char*)d_out + (size_t)N * 768); // [N][128] f16
  _Float16* mean1 = (_Float16*)((char*)d_out + (size_t)N * 512); // [N][256] f16
  _Float16* mean2 = (_Float16*)d_out;                            // [N][256] f16, pitch 512

  // CSR build
  int nzb = (N + 255) / 256;
  k_zero<<<nzb, 256, 0, stream>>>(deg, N);
  k_zero<<<nzb, 256, 0, stream>>>(cursor, N);
  k_deg<<<(E + 255) / 256, 256, 0, stream>>>(ei, deg, E);
  int nb = (N + 1023) / 1024;
  k_chunk_sum<<<nb, 256, 0, stream>>>(deg, bsum, N);
  k_scan_bsum<<<1, 64, 0, stream>>>(bsum, nb);
  k_scan_final<<<nb, 256, 0, stream>>>(deg, bsum, rs, dinv, N, E);
  k_fill<<<(E + 255) / 256, 256, 0, stream>>>(ei, rs, cursor, srcs, E);

  // casts
  k_cast_f16<<<((N * 128 / 4) + 255) / 256, 256, 0, stream>>>(feat, x0, N * 128 / 4);
  for (int l = 0; l < 3; l++) {
    int n4 = 256 * din[l] / 4;
    k_cast_f16<<<(n4 + 255) / 256, 256, 0, stream>>>(Wl[l], wlh[l], n4);
    k_cast_f16<<<(n4 + 255) / 256, 256, 0, stream>>>(Wr[l], wrh[l], n4);
  }

  int aggGrid = (N + 3) / 4;
  int gemmGrid = (N + 63) / 64;

  // Layer 0
  k_aggm<128, 128><<<aggGrid, 256, 0, stream>>>(x0, srcs, rs, dinv, mean0, N);
  k_gemm<256, 128, 128, false><<<gemmGrid, 256, 0, stream>>>(mean0, x0, wlh[0], wrh[0], Bv[0],
                                                             y0, nullptr, N);
  // Layer 1
  k_aggm<256, 256><<<aggGrid, 256, 0, stream>>>(y0, srcs, rs, dinv, mean1, N);
  k_gemm<512, 256, 256, false><<<gemmGrid, 256, 0, stream>>>(mean1, y0, wlh[1], wrh[1], Bv[1],
                                                             xbuf, nullptr, N);
  // Layer 2 (de-fused, interleaved in-place)
  k_aggm<256, 512><<<aggGrid, 256, 0, stream>>>(xbuf, srcs, rs, dinv, mean2, N);
  k_gemm<512, 256, 512, true><<<gemmGrid, 256, 0, stream>>>(mean2, xbuf, wlh[2], wrh[2], Bv[2],
                                                            nullptr, (float*)d_out, N);
}

// Round 10
// 705.178 us; speedup vs baseline: 8.6477x; 1.1937x over previous
//
#include <hip/hip_runtime.h>
#include <hip/hip_bf16.h>
#include <type_traits>

typedef _Float16 half8_t __attribute__((ext_vector_type(8)));
typedef _Float16 half4_t __attribute__((ext_vector_type(4)));
typedef _Float16 half2_t __attribute__((ext_vector_type(2)));
typedef float f32x4 __attribute__((ext_vector_type(4)));

// ---------------- CSR build ----------------
// harness delivers integer inputs as int32 (edge_index int64 -> const int*).

static __global__ __launch_bounds__(256) void k_zero(int* __restrict__ a, int n) {
  int i = blockIdx.x * 256 + threadIdx.x;
  if (i < n) a[i] = 0;
}

static __global__ __launch_bounds__(256) void k_deg(const int* __restrict__ ei,
                                                    int* __restrict__ deg, int E) {
  int e = blockIdx.x * 256 + threadIdx.x;
  if (e < E) atomicAdd(&deg[ei[E + e]], 1);  // dst = ei[1][e]
}

static __global__ __launch_bounds__(256) void k_chunk_sum(const int* __restrict__ deg,
                                                          int* __restrict__ bsum, int n) {
  int t = threadIdx.x;
  int base = blockIdx.x * 1024 + t * 4;
  int s = 0;
#pragma unroll
  for (int j = 0; j < 4; j++) {
    int idx = base + j;
    if (idx < n) s += deg[idx];
  }
  __shared__ int red[256];
  red[t] = s;
  __syncthreads();
  for (int off = 128; off > 0; off >>= 1) {
    if (t < off) red[t] += red[t + off];
    __syncthreads();
  }
  if (t == 0) bsum[blockIdx.x] = red[0];
}

static __global__ void k_scan_bsum(int* bsum, int nb) {
  if (threadIdx.x == 0 && blockIdx.x == 0) {
    int run = 0;
    for (int i = 0; i < nb; i++) {
      int v = bsum[i];
      bsum[i] = run;
      run += v;
    }
  }
}

static __global__ __launch_bounds__(256) void k_scan_final(const int* __restrict__ deg,
                                                           const int* __restrict__ bsum,
                                                           int* __restrict__ rs,
                                                           float* __restrict__ dinv,
                                                           int n, int Etot) {
  int t = threadIdx.x;
  int base = blockIdx.x * 1024 + t * 4;
  int v[4];
  int s = 0;
#pragma unroll
  for (int j = 0; j < 4; j++) {
    int idx = base + j;
    v[j] = (idx < n) ? deg[idx] : 0;
    s += v[j];
  }
  __shared__ int sc[256];
  sc[t] = s;
  __syncthreads();
  for (int off = 1; off < 256; off <<= 1) {
    int add = (t >= off) ? sc[t - off] : 0;
    __syncthreads();
    sc[t] += add;
    __syncthreads();
  }
  int run = sc[t] - s + bsum[blockIdx.x];
#pragma unroll
  for (int j = 0; j < 4; j++) {
    int idx = base + j;
    if (idx < n) {
      rs[idx] = run;
      dinv[idx] = v[j] > 0 ? 1.0f / (float)v[j] : 0.0f;
      run += v[j];
    }
  }
  if (blockIdx.x == 0 && t == 0) rs[n] = Etot;
}

static __global__ __launch_bounds__(256) void k_fill(const int* __restrict__ ei,
                                                     const int* __restrict__ rs,
                                                     int* __restrict__ cursor,
                                                     int* __restrict__ srcs, int E) {
  int e = blockIdx.x * 256 + threadIdx.x;
  if (e < E) {
    int d = ei[E + e];
    int s = ei[e];
    int pos = atomicAdd(&cursor[d], 1);
    srcs[rs[d] + pos] = s;
  }
}

// ---------------- casts ----------------

static __global__ __launch_bounds__(256) void k_cast_f16(const float* __restrict__ in,
                                                         _Float16* __restrict__ out, int n4) {
  int i = blockIdx.x * 256 + threadIdx.x;
  if (i < n4) {
    float4 v = reinterpret_cast<const float4*>(in)[i];
    half4_t h;
    h[0] = (_Float16)v.x;
    h[1] = (_Float16)v.y;
    h[2] = (_Float16)v.z;
    h[3] = (_Float16)v.w;
    reinterpret_cast<half4_t*>(out)[i] = h;
  }
}

// ---------------- high-occupancy mean aggregation (unchanged from round 8/9) ----------------

template <int DIN, int OSTR>
static __global__ __launch_bounds__(256) void k_aggm(const _Float16* __restrict__ x,
                                                     const int* __restrict__ srcs,
                                                     const int* __restrict__ rs,
                                                     const float* __restrict__ dinv,
                                                     _Float16* __restrict__ meanb, int n) {
  constexpr int EPL = DIN / 64;
  using hv = typename std::conditional<EPL == 2, half2_t, half4_t>::type;
  int lane = threadIdx.x & 63;
  int w = threadIdx.x >> 6;
  int i = blockIdx.x * 4 + w;
  if (i >= n) return;
  int e0 = rs[i], e1 = rs[i + 1];
  int co = lane * EPL;
  float acc[EPL];
#pragma unroll
  for (int j = 0; j < EPL; j++) acc[j] = 0.0f;
  for (int e = e0; e < e1; e += 8) {
    hv v[8];
#pragma unroll
    for (int k = 0; k < 8; k++) {
      int ee = e + k;
      ee = ee < e1 ? ee : e1 - 1;  // clamp (loop entered => e1-1 >= e0)
      v[k] = *(const hv*)(x + (size_t)srcs[ee] * DIN + co);
    }
#pragma unroll
    for (int k = 0; k < 8; k++) {
      if (e + k < e1) {  // wave-uniform predicate
#pragma unroll
        for (int j = 0; j < EPL; j++) acc[j] += (float)v[k][j];
      }
    }
  }
  float di = dinv[i];
  hv o;
#pragma unroll
  for (int j = 0; j < EPL; j++) o[j] = (_Float16)(acc[j] * di);
  *(hv*)(meanb + (size_t)i * OSTR + co) = o;
}

// ---------------- dual GEMM + bias + relu, LDS-staged ----------------
// Block 256 thr = 4 waves; tile 64 rows x 256 cols; wave tile 64x64.
// Per BK=64 chunk: cooperatively stage A[64][64] (8KB) + B[256][64] (32KB) into LDS
// with coalesced 16B loads; XOR-swizzle byte^((row&7)<<4) on write AND read keeps
// ds_read_b128 fragment reads at 2-way bank aliasing (free). 32 MFMA per chunk.
// For LAST (in-place over interleaved mean2 in d_out): all global A-reads of the
// final chunk complete before the post-staging barrier; f32 stores come after all
// MFMA and touch only this block's rows [i0,i0+64) -> no read-after-overwrite.

template <int K2, int DIN, int ASTR, bool LAST>
static __global__ __launch_bounds__(256) void k_gemm(const _Float16* __restrict__ meanb,
                                                     const _Float16* __restrict__ xb,
                                                     const _Float16* __restrict__ wlh,
                                                     const _Float16* __restrict__ wrh,
                                                     const float* __restrict__ bias,
                                                     _Float16* __restrict__ yout,
                                                     float* __restrict__ fout, int M) {
  __shared__ __align__(16) _Float16 As[64 * 64];   // 8 KB
  __shared__ __align__(16) _Float16 Bs[256 * 64];  // 32 KB
  int t = threadIdx.x;
  int lane = t & 63;
  int w = t >> 6;
  int i0 = blockIdx.x * 64;
  int n0 = w * 64;
  int lr = lane & 15;
  int kq = lane >> 4;
  f32x4 acc[4][4];
#pragma unroll
  for (int m = 0; m < 4; m++)
#pragma unroll
    for (int nn = 0; nn < 4; nn++) acc[m][nn] = (f32x4)0.0f;

  for (int c = 0; c < K2 / 64; ++c) {
    int k0 = c * 64;
    const _Float16* Ab;
    const _Float16* Bb;
    int ap;
    if (k0 < DIN) {
      Ab = meanb + k0;
      ap = ASTR;
      Bb = wlh + k0;
    } else {
      Ab = xb + (k0 - DIN);
      ap = DIN;
      Bb = wrh + (k0 - DIN);
    }
    // stage A: 512 x 16B, 2 iters x 256 threads
#pragma unroll
    for (int it = 0; it < 2; ++it) {
      int idx = it * 256 + t;
      int row = idx >> 3, u = idx & 7;
      int grow = i0 + row;
      if (grow >= M) grow = M - 1;
      half8_t v = *(const half8_t*)(Ab + (size_t)grow * ap + u * 8);
      *(half8_t*)((char*)As + row * 128 + ((u * 16) ^ ((row & 7) << 4))) = v;
    }
    // stage B: 2048 x 16B, 8 iters x 256 threads
#pragma unroll
    for (int it = 0; it < 8; ++it) {
      int idx = it * 256 + t;
      int col = idx >> 3, u = idx & 7;
      half8_t v = *(const half8_t*)(Bb + (size_t)col * DIN + u * 8);
      *(half8_t*)((char*)Bs + col * 128 + ((u * 16) ^ ((col & 7) << 4))) = v;
    }
    __syncthreads();
#pragma unroll
    for (int kk = 0; kk < 2; ++kk) {
      int kb = kk * 64 + kq * 16;  // byte offset of this lane's 16B k-slice
      half8_t a[4], b[4];
#pragma unroll
      for (int m = 0; m < 4; m++) {
        int r = m * 16 + lr;
        a[m] = *(const half8_t*)((char*)As + r * 128 + (kb ^ ((r & 7) << 4)));
      }
#pragma unroll
      for (int nn = 0; nn < 4; nn++) {
        int cl = n0 + nn * 16 + lr;
        b[nn] = *(const half8_t*)((char*)Bs + cl * 128 + (kb ^ ((cl & 7) << 4)));
      }
#pragma unroll
      for (int m = 0; m < 4; m++)
#pragma unroll
        for (int nn = 0; nn < 4; nn++)
          acc[m][nn] = __builtin_amdgcn_mfma_f32_16x16x32_f16(a[m], b[nn], acc[m][nn], 0, 0, 0);
    }
    __syncthreads();
  }

  // ---- epilogue ----
#pragma unroll
  for (int nn = 0; nn < 4; nn++) {
    int col = n0 + nn * 16 + lr;  // D col = lane&15
    float bv = bias[col];
#pragma unroll
    for (int m = 0; m < 4; m++) {
#pragma unroll
      for (int r = 0; r < 4; r++) {
        int row = i0 + m * 16 + kq * 4 + r;  // D row = (lane>>4)*4 + r
        if (row < M) {
          float v = acc[m][nn][r] + bv;
          v = v > 0.0f ? v : 0.0f;
          if constexpr (LAST)
            fout[(size_t)row * 256 + col] = v;
          else
            yout[(size_t)row * 256 + col] = (_Float16)v;
        }
      }
    }
  }
}

// ---------------- host launch ----------------
// ws (61 MB, proven safe): xbuf(51.2M)=x1  srcs(6.4M) rs deg cursor dinv bsum weights(f16)
// d_out (N*1024 B) timeline per call (every region written before read, no cross-call state):
//   cast:  x0 f16 [N][128] at bytes [512N,768N)
//   agg0:  mean0 f16 [N][128] at [768N,1024N)          (reads x0)
//   gemm0: y0 f16 [N][256] at [0,512N)                 (reads mean0,x0; disjoint)
//   agg1:  mean1 f16 [N][256] at [512N,1024N)          (reads y0; overwrites dead x0/mean0)
//   gemm1: x1 f16 -> ws.xbuf                           (reads mean1,y0)
//   agg2:  mean2 f16 [N][256] INTERLEAVED: row r = first 512B of each 1024B d_out row
//          (reads ws.xbuf only; overwrites dead y0/mean1)
//   gemm2: f32 [N][256] over all of d_out, in-place per block (reads mean2 rows
//          [i0,i0+64) into LDS before the staging barrier; stores after; no
//          cross-block overlap)

extern "C" void kernel_launch(void* const* d_in, const int* in_sizes, int n_in,
                              void* d_out, int out_size, void* d_ws, size_t ws_size,
                              hipStream_t stream) {
  const float* feat = (const float*)d_in[0];
  const int* ei = (const int*)d_in[1];
  const float* Wl[3] = {(const float*)d_in[2], (const float*)d_in[5], (const float*)d_in[8]};
  const float* Wr[3] = {(const float*)d_in[3], (const float*)d_in[6], (const float*)d_in[9]};
  const float* Bv[3] = {(const float*)d_in[4], (const float*)d_in[7], (const float*)d_in[10]};
  int N = in_sizes[0] / 128;
  int E = in_sizes[1] / 2;

  char* p = (char*)d_ws;
  auto carve = [&](size_t bytes) {
    char* r = p;
    p += (bytes + 255) & ~(size_t)255;
    return r;
  };
  _Float16* xbuf = (_Float16*)carve((size_t)N * 256 * 2);  // x1 = layer-1 output
  int* srcs = (int*)carve((size_t)E * 4);
  int* rs = (int*)carve((size_t)(N + 1) * 4);
  int* deg = (int*)carve((size_t)N * 4);
  int* cursor = (int*)carve((size_t)N * 4);
  float* dinv = (float*)carve((size_t)N * 4);
  int* bsum = (int*)carve(4096);
  const int din[3] = {128, 256, 256};
  _Float16* wlh[3];
  _Float16* wrh[3];
  for (int l = 0; l < 3; l++) {
    wlh[l] = (_Float16*)carve((size_t)256 * din[l] * 2);
    wrh[l] = (_Float16*)carve((size_t)256 * din[l] * 2);
  }

  _Float16* y0 = (_Float16*)d_out;                               // [N][256] f16
  _Float16* x0 = (_Float16*)((char*)d_out + (size_t)N * 512);    // [N][128] f16
  _Float16* mean0 = (_Float16*)((char*)d_out + (size_t)N * 768); // [N][128] f16
  _Float16* mean1 = (_Float16*)((char*)d_out + (size_t)N * 512); // [N][256] f16
  _Float16* mean2 = (_Float16*)d_out;                            // [N][256] f16, pitch 512

  // CSR build
  int nzb = (N + 255) / 256;
  k_zero<<<nzb, 256, 0, stream>>>(deg, N);
  k_zero<<<nzb, 256, 0, stream>>>(cursor, N);
  k_deg<<<(E + 255) / 256, 256, 0, stream>>>(ei, deg, E);
  int nb = (N + 1023) / 1024;
  k_chunk_sum<<<nb, 256, 0, stream>>>(deg, bsum, N);
  k_scan_bsum<<<1, 64, 0, stream>>>(bsum, nb);
  k_scan_final<<<nb, 256, 0, stream>>>(deg, bsum, rs, dinv, N, E);
  k_fill<<<(E + 255) / 256, 256, 0, stream>>>(ei, rs, cursor, srcs, E);

  // casts
  k_cast_f16<<<((N * 128 / 4) + 255) / 256, 256, 0, stream>>>(feat, x0, N * 128 / 4);
  for (int l = 0; l < 3; l++) {
    int n4 = 256 * din[l] / 4;
    k_cast_f16<<<(n4 + 255) / 256, 256, 0, stream>>>(Wl[l], wlh[l], n4);
    k_cast_f16<<<(n4 + 255) / 256, 256, 0, stream>>>(Wr[l], wrh[l], n4);
  }

  int aggGrid = (N + 3) / 4;
  int gemmGrid = (N + 63) / 64;

  // Layer 0
  k_aggm<128, 128><<<aggGrid, 256, 0, stream>>>(x0, srcs, rs, dinv, mean0, N);
  k_gemm<256, 128, 128, false><<<gemmGrid, 256, 0, stream>>>(mean0, x0, wlh[0], wrh[0], Bv[0],
                                                             y0, nullptr, N);
  // Layer 1
  k_aggm<256, 256><<<aggGrid, 256, 0, stream>>>(y0, srcs, rs, dinv, mean1, N);
  k_gemm<512, 256, 256, false><<<gemmGrid, 256, 0, stream>>>(mean1, y0, wlh[1], wrh[1], Bv[1],
                                                             xbuf, nullptr, N);
  // Layer 2 (interleaved in-place)
  k_aggm<256, 512><<<aggGrid, 256, 0, stream>>>(xbuf, srcs, rs, dinv, mean2, N);
  k_gemm<512, 256, 512, true><<<gemmGrid, 256, 0, stream>>>(mean2, xbuf, wlh[2], wrh[2], Bv[2],
                                                            nullptr, (float*)d_out, N);
}

// Round 11
// 667.729 us; speedup vs baseline: 9.1326x; 1.0561x over previous
//
#include <hip/hip_runtime.h>
#include <hip/hip_bf16.h>
#include <type_traits>

typedef _Float16 half8_t __attribute__((ext_vector_type(8)));
typedef _Float16 half4_t __attribute__((ext_vector_type(4)));
typedef _Float16 half2_t __attribute__((ext_vector_type(2)));
typedef float f32x4 __attribute__((ext_vector_type(4)));

// ---------------- CSR build ----------------
// harness delivers integer inputs as int32 (edge_index int64 -> const int*).
// k_deg2/k_fill2: dst-slice-partitioned scatter. Grid g = chunk*8 + slice; consecutive
// blocks (round-robin over the 8 XCDs) own distinct dst slices, so each slice of the
// deg/cursor/srcs arrays is touched by (mostly) one XCD's L2 -> full-line writebacks
// instead of 16x cross-XCD false-sharing amplification. 8x re-read of ei is L3-served.

static __global__ __launch_bounds__(256) void k_zero(int* __restrict__ a, int n) {
  int i = blockIdx.x * 256 + threadIdx.x;
  if (i < n) a[i] = 0;
}

static __global__ __launch_bounds__(256) void k_deg2(const int* __restrict__ ei,
                                                     int* __restrict__ deg, int E, int ssz) {
  int sl = blockIdx.x & 7;
  int lo = sl * ssz, hi = lo + ssz;
  int base = (blockIdx.x >> 3) * 2048 + threadIdx.x;
#pragma unroll
  for (int k = 0; k < 8; ++k) {
    int e = base + k * 256;
    if (e < E) {
      int d = ei[E + e];
      if (d >= lo && d < hi) atomicAdd(&deg[d], 1);
    }
  }
}

static __global__ __launch_bounds__(256) void k_chunk_sum(const int* __restrict__ deg,
                                                          int* __restrict__ bsum, int n) {
  int t = threadIdx.x;
  int base = blockIdx.x * 1024 + t * 4;
  int s = 0;
#pragma unroll
  for (int j = 0; j < 4; j++) {
    int idx = base + j;
    if (idx < n) s += deg[idx];
  }
  __shared__ int red[256];
  red[t] = s;
  __syncthreads();
  for (int off = 128; off > 0; off >>= 1) {
    if (t < off) red[t] += red[t + off];
    __syncthreads();
  }
  if (t == 0) bsum[blockIdx.x] = red[0];
}

static __global__ void k_scan_bsum(int* bsum, int nb) {
  if (threadIdx.x == 0 && blockIdx.x == 0) {
    int run = 0;
    for (int i = 0; i < nb; i++) {
      int v = bsum[i];
      bsum[i] = run;
      run += v;
    }
  }
}

static __global__ __launch_bounds__(256) void k_scan_final(const int* __restrict__ deg,
                                                           const int* __restrict__ bsum,
                                                           int* __restrict__ rs,
                                                           float* __restrict__ dinv,
                                                           int n, int Etot) {
  int t = threadIdx.x;
  int base = blockIdx.x * 1024 + t * 4;
  int v[4];
  int s = 0;
#pragma unroll
  for (int j = 0; j < 4; j++) {
    int idx = base + j;
    v[j] = (idx < n) ? deg[idx] : 0;
    s += v[j];
  }
  __shared__ int sc[256];
  sc[t] = s;
  __syncthreads();
  for (int off = 1; off < 256; off <<= 1) {
    int add = (t >= off) ? sc[t - off] : 0;
    __syncthreads();
    sc[t] += add;
    __syncthreads();
  }
  int run = sc[t] - s + bsum[blockIdx.x];
#pragma unroll
  for (int j = 0; j < 4; j++) {
    int idx = base + j;
    if (idx < n) {
      rs[idx] = run;
      dinv[idx] = v[j] > 0 ? 1.0f / (float)v[j] : 0.0f;
      run += v[j];
    }
  }
  if (blockIdx.x == 0 && t == 0) rs[n] = Etot;
}

static __global__ __launch_bounds__(256) void k_fill2(const int* __restrict__ ei,
                                                      const int* __restrict__ rs,
                                                      int* __restrict__ cursor,
                                                      int* __restrict__ srcs, int E, int ssz) {
  int sl = blockIdx.x & 7;
  int lo = sl * ssz, hi = lo + ssz;
  int base = (blockIdx.x >> 3) * 2048 + threadIdx.x;
#pragma unroll
  for (int k = 0; k < 8; ++k) {
    int e = base + k * 256;
    if (e < E) {
      int d = ei[E + e];
      if (d >= lo && d < hi) {
        int pos = atomicAdd(&cursor[d], 1);
        srcs[rs[d] + pos] = ei[e];
      }
    }
  }
}

// ---------------- casts ----------------

static __global__ __launch_bounds__(256) void k_cast_f16(const float* __restrict__ in,
                                                         _Float16* __restrict__ out, int n4) {
  int i = blockIdx.x * 256 + threadIdx.x;
  if (i < n4) {
    float4 v = reinterpret_cast<const float4*>(in)[i];
    half4_t h;
    h[0] = (_Float16)v.x;
    h[1] = (_Float16)v.y;
    h[2] = (_Float16)v.z;
    h[3] = (_Float16)v.w;
    reinterpret_cast<half4_t*>(out)[i] = h;
  }
}

// ---------------- high-occupancy mean aggregation (unchanged) ----------------

template <int DIN, int OSTR>
static __global__ __launch_bounds__(256) void k_aggm(const _Float16* __restrict__ x,
                                                     const int* __restrict__ srcs,
                                                     const int* __restrict__ rs,
                                                     const float* __restrict__ dinv,
                                                     _Float16* __restrict__ meanb, int n) {
  constexpr int EPL = DIN / 64;
  using hv = typename std::conditional<EPL == 2, half2_t, half4_t>::type;
  int lane = threadIdx.x & 63;
  int w = threadIdx.x >> 6;
  int i = blockIdx.x * 4 + w;
  if (i >= n) return;
  int e0 = rs[i], e1 = rs[i + 1];
  int co = lane * EPL;
  float acc[EPL];
#pragma unroll
  for (int j = 0; j < EPL; j++) acc[j] = 0.0f;
  for (int e = e0; e < e1; e += 8) {
    hv v[8];
#pragma unroll
    for (int k = 0; k < 8; k++) {
      int ee = e + k;
      ee = ee < e1 ? ee : e1 - 1;  // clamp (loop entered => e1-1 >= e0)
      v[k] = *(const hv*)(x + (size_t)srcs[ee] * DIN + co);
    }
#pragma unroll
    for (int k = 0; k < 8; k++) {
      if (e + k < e1) {  // wave-uniform predicate
#pragma unroll
        for (int j = 0; j < EPL; j++) acc[j] += (float)v[k][j];
      }
    }
  }
  float di = dinv[i];
  hv o;
#pragma unroll
  for (int j = 0; j < EPL; j++) o[j] = (_Float16)(acc[j] * di);
  *(hv*)(meanb + (size_t)i * OSTR + co) = o;
}

// ---------------- dual GEMM + bias + relu, LDS-staged (unchanged from round 10) ----------------

template <int K2, int DIN, int ASTR, bool LAST>
static __global__ __launch_bounds__(256) void k_gemm(const _Float16* __restrict__ meanb,
                                                     const _Float16* __restrict__ xb,
                                                     const _Float16* __restrict__ wlh,
                                                     const _Float16* __restrict__ wrh,
                                                     const float* __restrict__ bias,
                                                     _Float16* __restrict__ yout,
                                                     float* __restrict__ fout, int M) {
  __shared__ __align__(16) _Float16 As[64 * 64];   // 8 KB
  __shared__ __align__(16) _Float16 Bs[256 * 64];  // 32 KB
  int t = threadIdx.x;
  int lane = t & 63;
  int w = t >> 6;
  int i0 = blockIdx.x * 64;
  int n0 = w * 64;
  int lr = lane & 15;
  int kq = lane >> 4;
  f32x4 acc[4][4];
#pragma unroll
  for (int m = 0; m < 4; m++)
#pragma unroll
    for (int nn = 0; nn < 4; nn++) acc[m][nn] = (f32x4)0.0f;

  for (int c = 0; c < K2 / 64; ++c) {
    int k0 = c * 64;
    const _Float16* Ab;
    const _Float16* Bb;
    int ap;
    if (k0 < DIN) {
      Ab = meanb + k0;
      ap = ASTR;
      Bb = wlh + k0;
    } else {
      Ab = xb + (k0 - DIN);
      ap = DIN;
      Bb = wrh + (k0 - DIN);
    }
    // stage A: 512 x 16B, 2 iters x 256 threads
#pragma unroll
    for (int it = 0; it < 2; ++it) {
      int idx = it * 256 + t;
      int row = idx >> 3, u = idx & 7;
      int grow = i0 + row;
      if (grow >= M) grow = M - 1;
      half8_t v = *(const half8_t*)(Ab + (size_t)grow * ap + u * 8);
      *(half8_t*)((char*)As + row * 128 + ((u * 16) ^ ((row & 7) << 4))) = v;
    }
    // stage B: 2048 x 16B, 8 iters x 256 threads
#pragma unroll
    for (int it = 0; it < 8; ++it) {
      int idx = it * 256 + t;
      int col = idx >> 3, u = idx & 7;
      half8_t v = *(const half8_t*)(Bb + (size_t)col * DIN + u * 8);
      *(half8_t*)((char*)Bs + col * 128 + ((u * 16) ^ ((col & 7) << 4))) = v;
    }
    __syncthreads();
#pragma unroll
    for (int kk = 0; kk < 2; ++kk) {
      int kb = kk * 64 + kq * 16;  // byte offset of this lane's 16B k-slice
      half8_t a[4], b[4];
#pragma unroll
      for (int m = 0; m < 4; m++) {
        int r = m * 16 + lr;
        a[m] = *(const half8_t*)((char*)As + r * 128 + (kb ^ ((r & 7) << 4)));
      }
#pragma unroll
      for (int nn = 0; nn < 4; nn++) {
        int cl = n0 + nn * 16 + lr;
        b[nn] = *(const half8_t*)((char*)Bs + cl * 128 + (kb ^ ((cl & 7) << 4)));
      }
#pragma unroll
      for (int m = 0; m < 4; m++)
#pragma unroll
        for (int nn = 0; nn < 4; nn++)
          acc[m][nn] = __builtin_amdgcn_mfma_f32_16x16x32_f16(a[m], b[nn], acc[m][nn], 0, 0, 0);
    }
    __syncthreads();
  }

  // ---- epilogue ----
#pragma unroll
  for (int nn = 0; nn < 4; nn++) {
    int col = n0 + nn * 16 + lr;  // D col = lane&15
    float bv = bias[col];
#pragma unroll
    for (int m = 0; m < 4; m++) {
#pragma unroll
      for (int r = 0; r < 4; r++) {
        int row = i0 + m * 16 + kq * 4 + r;  // D row = (lane>>4)*4 + r
        if (row < M) {
          float v = acc[m][nn][r] + bv;
          v = v > 0.0f ? v : 0.0f;
          if constexpr (LAST)
            fout[(size_t)row * 256 + col] = v;
          else
            yout[(size_t)row * 256 + col] = (_Float16)v;
        }
      }
    }
  }
}

// ---------------- host launch ----------------
// ws (61 MB, proven safe): xbuf(51.2M)=x1  srcs(6.4M) rs deg cursor dinv bsum weights(f16)
// d_out (N*1024 B) timeline per call (every region written before read, no cross-call state):
//   cast:  x0 f16 [N][128] at bytes [512N,768N)
//   agg0:  mean0 f16 [N][128] at [768N,1024N)          (reads x0)
//   gemm0: y0 f16 [N][256] at [0,512N)                 (reads mean0,x0; disjoint)
//   agg1:  mean1 f16 [N][256] at [512N,1024N)          (reads y0; overwrites dead x0/mean0)
//   gemm1: x1 f16 -> ws.xbuf                           (reads mean1,y0)
//   agg2:  mean2 f16 [N][256] INTERLEAVED: row r = first 512B of each 1024B d_out row
//          (reads ws.xbuf only; overwrites dead y0/mean1)
//   gemm2: f32 [N][256] over all of d_out, in-place per block (reads mean2 rows
//          [i0,i0+64) into LDS before the staging barrier; stores after; no
//          cross-block overlap)

extern "C" void kernel_launch(void* const* d_in, const int* in_sizes, int n_in,
                              void* d_out, int out_size, void* d_ws, size_t ws_size,
                              hipStream_t stream) {
  const float* feat = (const float*)d_in[0];
  const int* ei = (const int*)d_in[1];
  const float* Wl[3] = {(const float*)d_in[2], (const float*)d_in[5], (const float*)d_in[8]};
  const float* Wr[3] = {(const float*)d_in[3], (const float*)d_in[6], (const float*)d_in[9]};
  const float* Bv[3] = {(const float*)d_in[4], (const float*)d_in[7], (const float*)d_in[10]};
  int N = in_sizes[0] / 128;
  int E = in_sizes[1] / 2;

  char* p = (char*)d_ws;
  auto carve = [&](size_t bytes) {
    char* r = p;
    p += (bytes + 255) & ~(size_t)255;
    return r;
  };
  _Float16* xbuf = (_Float16*)carve((size_t)N * 256 * 2);  // x1 = layer-1 output
  int* srcs = (int*)carve((size_t)E * 4);
  int* rs = (int*)carve((size_t)(N + 1) * 4);
  int* deg = (int*)carve((size_t)N * 4);
  int* cursor = (int*)carve((size_t)N * 4);
  float* dinv = (float*)carve((size_t)N * 4);
  int* bsum = (int*)carve(4096);
  const int din[3] = {128, 256, 256};
  _Float16* wlh[3];
  _Float16* wrh[3];
  for (int l = 0; l < 3; l++) {
    wlh[l] = (_Float16*)carve((size_t)256 * din[l] * 2);
    wrh[l] = (_Float16*)carve((size_t)256 * din[l] * 2);
  }

  _Float16* y0 = (_Float16*)d_out;                               // [N][256] f16
  _Float16* x0 = (_Float16*)((char*)d_out + (size_t)N * 512);    // [N][128] f16
  _Float16* mean0 = (_Float16*)((char*)d_out + (size_t)N * 768); // [N][128] f16
  _Float16* mean1 = (_Float16*)((char*)d_out + (size_t)N * 512); // [N][256] f16
  _Float16* mean2 = (_Float16*)d_out;                            // [N][256] f16, pitch 512

  // CSR build (slice-partitioned scatter kernels)
  int ssz = (N + 7) / 8;                  // dst-slice size
  int nchunk = (E + 2047) / 2048;
  int nzb = (N + 255) / 256;
  k_zero<<<nzb, 256, 0, stream>>>(deg, N);
  k_zero<<<nzb, 256, 0, stream>>>(cursor, N);
  k_deg2<<<nchunk * 8, 256, 0, stream>>>(ei, deg, E, ssz);
  int nb = (N + 1023) / 1024;
  k_chunk_sum<<<nb, 256, 0, stream>>>(deg, bsum, N);
  k_scan_bsum<<<1, 64, 0, stream>>>(bsum, nb);
  k_scan_final<<<nb, 256, 0, stream>>>(deg, bsum, rs, dinv, N, E);
  k_fill2<<<nchunk * 8, 256, 0, stream>>>(ei, rs, cursor, srcs, E, ssz);

  // casts
  k_cast_f16<<<((N * 128 / 4) + 255) / 256, 256, 0, stream>>>(feat, x0, N * 128 / 4);
  for (int l = 0; l < 3; l++) {
    int n4 = 256 * din[l] / 4;
    k_cast_f16<<<(n4 + 255) / 256, 256, 0, stream>>>(Wl[l], wlh[l], n4);
    k_cast_f16<<<(n4 + 255) / 256, 256, 0, stream>>>(Wr[l], wrh[l], n4);
  }

  int aggGrid = (N + 3) / 4;
  int gemmGrid = (N + 63) / 64;

  // Layer 0
  k_aggm<128, 128><<<aggGrid, 256, 0, stream>>>(x0, srcs, rs, dinv, mean0, N);
  k_gemm<256, 128, 128, false><<<gemmGrid, 256, 0, stream>>>(mean0, x0, wlh[0], wrh[0], Bv[0],
                                                             y0, nullptr, N);
  // Layer 1
  k_aggm<256, 256><<<aggGrid, 256, 0, stream>>>(y0, srcs, rs, dinv, mean1, N);
  k_gemm<512, 256, 256, false><<<gemmGrid, 256, 0, stream>>>(mean1, y0, wlh[1], wrh[1], Bv[1],
                                                             xbuf, nullptr, N);
  // Layer 2 (interleaved in-place)
  k_aggm<256, 512><<<aggGrid, 256, 0, stream>>>(xbuf, srcs, rs, dinv, mean2, N);
  k_gemm<512, 256, 512, true><<<gemmGrid, 256, 0, stream>>>(mean2, xbuf, wlh[2], wrh[2], Bv[2],
                                                            nullptr, (float*)d_out, N);
}